// Round 15
// baseline (464.781 us; speedup 1.0000x reference)
//
#include <hip/hip_runtime.h>
#include <stdint.h>

#define BW   128      // nodes per bucket
#define NBM  625      // movie buckets  (80000/128)
#define NBU  1563     // user buckets   (ceil 200000/128)
#define CAPM 4096     // per-bucket capacity, movie (avg 3200)
#define CAPU 2048     // per-bucket capacity, user  (avg 1280)

typedef __attribute__((ext_vector_type(8))) short bf16x8;
typedef __attribute__((ext_vector_type(4))) float f32x4;

__device__ __forceinline__ float b2f(ushort u) {
    return __uint_as_float((uint32_t)u << 16);
}
__device__ __forceinline__ ushort f2b(float f) {
    uint32_t x = __float_as_uint(f);
    return (ushort)((x + 0x7FFFu + ((x >> 16) & 1u)) >> 16);   // RNE
}
__device__ __forceinline__ float lo16f(uint32_t v) { return __uint_as_float(v << 16); }
__device__ __forceinline__ float hi16f(uint32_t v) { return __uint_as_float(v & 0xFFFF0000u); }
__device__ __forceinline__ uint32_t packbf2(float x, float y) {
    return (uint32_t)f2b(x) | ((uint32_t)f2b(y) << 16);
}

// ---------------- edge binning: bucket-major edge lists, both directions ----------------
__global__ __launch_bounds__(256) void bin_kernel(
    const int* __restrict__ src, const int* __restrict__ dst, int E,
    int* __restrict__ gcm, int* __restrict__ gcu,
    uint32_t* __restrict__ Bm, uint32_t* __restrict__ Bu)
{
    __shared__ int hm[NBM], hu[NBU];
    const int CH = 8192;
    int e0 = blockIdx.x * CH;
    int e1 = min(e0 + CH, E);
    int tid = threadIdx.x;
    for (int b = tid; b < NBM; b += 256) hm[b] = 0;
    for (int b = tid; b < NBU; b += 256) hu[b] = 0;
    __syncthreads();
    for (int i = e0 + tid; i < e1; i += 256) {
        atomicAdd(&hm[dst[i] >> 7], 1);
        atomicAdd(&hu[src[i] >> 7], 1);
    }
    __syncthreads();
    for (int b = tid; b < NBM; b += 256) { int c = hm[b]; hm[b] = c ? atomicAdd(&gcm[b], c) : 0; }
    for (int b = tid; b < NBU; b += 256) { int c = hu[b]; hu[b] = c ? atomicAdd(&gcu[b], c) : 0; }
    __syncthreads();
    for (int i = e0 + tid; i < e1; i += 256) {
        int d = dst[i], s = src[i];
        int bm = d >> 7, bu = s >> 7;
        int pm = atomicAdd(&hm[bm], 1);
        if (pm < CAPM) Bm[(size_t)bm * CAPM + pm] = ((uint32_t)(d & 127) << 24) | (uint32_t)s;
        int pu = atomicAdd(&hu[bu], 1);
        if (pu < CAPU) Bu[(size_t)bu * CAPU + pu] = ((uint32_t)(s & 127) << 24) | (uint32_t)d;
    }
}

// ---------------- merged per-bucket counting sort -> node-ordered payload(<<5) + local offsets ----------------
__global__ __launch_bounds__(256) void sort_bucket2(
    uint32_t* __restrict__ Bm, const int* __restrict__ gcm, int* __restrict__ loffm,
    uint32_t* __restrict__ Bu, const int* __restrict__ gcu, int* __restrict__ loffu)
{
    __shared__ uint32_t rec[CAPM];
    __shared__ uint32_t srt[CAPM];
    __shared__ int hist[BW];
    __shared__ int hoff[BW + 1];
    __shared__ int cur[BW];
    int bid = blockIdx.x, tid = threadIdx.x;
    uint32_t* B; const int* gc; int* loff; int cap; int b;
    if (bid < NBM) { B = Bm; gc = gcm; loff = loffm; cap = CAPM; b = bid; }
    else           { B = Bu; gc = gcu; loff = loffu; cap = CAPU; b = bid - NBM; }
    int cnt = min(gc[b], cap);
    uint32_t* bp = B + (size_t)b * cap;
    for (int i = tid; i < cnt; i += 256) rec[i] = bp[i];
    if (tid < BW) hist[tid] = 0;
    __syncthreads();
    for (int i = tid; i < cnt; i += 256) atomicAdd(&hist[rec[i] >> 24], 1);
    __syncthreads();
    if (tid == 0) {
        int s = 0;
        for (int i = 0; i < BW; ++i) { hoff[i] = s; s += hist[i]; }
        hoff[BW] = s;
    }
    __syncthreads();
    if (tid < BW) cur[tid] = hoff[tid];
    __syncthreads();
    for (int i = tid; i < cnt; i += 256) {
        uint32_t r = rec[i];
        int pos = atomicAdd(&cur[r >> 24], 1);
        srt[pos] = (r & 0xFFFFFFu) << 5;   // pre-scaled: uint32-word offset of table row
    }
    __syncthreads();
    for (int i = tid; i < cnt; i += 256) bp[i] = srt[i];
    for (int i = tid; i <= BW; i += 256) loff[(size_t)b * (BW + 1) + i] = hoff[i];
}

// ---------------- merged weight prep: 4x (64x64 collapse -> bf16 transposed) + 2x (128x128 transpose) ----------------
__global__ __launch_bounds__(256) void wprep(
    const float* __restrict__ W2ml, const float* __restrict__ W2mr,
    const float* __restrict__ W2ul, const float* __restrict__ W2ur,
    const float* __restrict__ Wd1, const float* __restrict__ bd1,
    const float* __restrict__ b2m, const float* __restrict__ b2u,
    const float* __restrict__ W1ul, const float* __restrict__ W1mr,
    const float* __restrict__ W1ml, const float* __restrict__ W1ur,
    ushort* __restrict__ Wt2_m, ushort* __restrict__ Wt2_u,
    ushort* __restrict__ Wt_u, ushort* __restrict__ Wt_m,
    float* __restrict__ cu, float* __restrict__ cm)
{
    __shared__ float As[4096], Bs[4096];
    int bid = blockIdx.x, tid = threadIdx.x;
    if (bid < 4) {
        const float* A; int brow0; const float* bvec; const float* addb;
        ushort* WtOut; int cofs; float* outc;
        if (bid == 0)      { A = W2ml; brow0 = 0;  bvec = b2m; addb = bd1;    WtOut = Wt2_m; cofs = 0;  outc = cu; }
        else if (bid == 1) { A = W2mr; brow0 = 0;  bvec = 0;   addb = 0;      WtOut = Wt2_u; cofs = 0;  outc = 0;  }
        else if (bid == 2) { A = W2ul; brow0 = 64; bvec = b2u; addb = 0;      WtOut = Wt2_u; cofs = 64; outc = cm; }
        else               { A = W2ur; brow0 = 64; bvec = 0;   addb = 0;      WtOut = Wt2_m; cofs = 64; outc = 0;  }
        for (int i = tid; i < 4096; i += 256) {
            As[i] = A[i];
            Bs[i] = Wd1[(size_t)(brow0 + (i >> 6)) * 64 + (i & 63)];
        }
        __syncthreads();
        int r = tid >> 2, c0 = (tid & 3) * 16;
        float acc[16] = {};
        for (int k = 0; k < 64; ++k) {
            float a = As[r * 64 + k];
            const float* bp = &Bs[k * 64 + c0];
#pragma unroll
            for (int j = 0; j < 16; ++j) acc[j] += a * bp[j];
        }
#pragma unroll
        for (int j = 0; j < 16; ++j)
            WtOut[(size_t)(cofs + c0 + j) * 64 + r] = f2b(acc[j]);   // [c][k] bf16, transposed
        if (outc && tid < 64) {
            float s = addb ? addb[tid] : 0.f;
            for (int k = 0; k < 64; ++k) s += bvec[k] * Bs[k * 64 + tid];
            outc[tid] = s;
        }
    } else {
        int t = bid - 4;
        const float *Wa, *Wb; ushort* Wt;
        if (t < 64) { Wa = W1ul; Wb = W1mr; Wt = Wt_u; }
        else        { Wa = W1ml; Wb = W1ur; Wt = Wt_m; t -= 64; }
        int idx = t * 256 + tid;           // 0 .. 16383 = 128 cols x 128 k
        int c = idx >> 7, k = idx & 127;
        Wt[idx] = f2b((c < 64 ? Wa : Wb)[(size_t)k * 64 + (c & 63)]);
    }
}

// ---------------- merged wave-per-node mean-aggregate: 16 lanes/edge, uint2, 32-deep main loop ----------------
template<int RELU>
__global__ __launch_bounds__(256) void agg_csr(
    const uint32_t* __restrict__ Ba, const int* __restrict__ loffa, int capa,
    const uint32_t* __restrict__ ta, const uint32_t* __restrict__ sa,
    const float* __restrict__ biasa, uint32_t* __restrict__ oa, int na, int GA,
    const uint32_t* __restrict__ Bb, const int* __restrict__ loffb, int capb,
    const uint32_t* __restrict__ tb, const uint32_t* __restrict__ sb,
    const float* __restrict__ biasb, uint32_t* __restrict__ ob, int nb)
{
    int bid = blockIdx.x;
    const uint32_t* B; const int* loff; int cap;
    const uint32_t* table; const uint32_t* self; const float* bias;
    uint32_t* out; int n_nodes; int lb;
    if (bid < GA) { B = Ba; loff = loffa; cap = capa; table = ta; self = sa; bias = biasa; out = oa; n_nodes = na; lb = bid; }
    else          { B = Bb; loff = loffb; cap = capb; table = tb; self = sb; bias = biasb; out = ob; n_nodes = nb; lb = bid - GA; }
    int node = lb * 4 + (threadIdx.x >> 6);
    if (node >= n_nodes) return;
    int lane = threadIdx.x & 63;
    int eq = lane >> 4;           // edge slot 0..3
    int fq = lane & 15;           // feature quad (4 bf16 = uint2)
    int b = node >> 7, l = node & 127;
    const int* lo = loff + (size_t)b * (BW + 1);
    int beg = lo[l], end = lo[l + 1];
    const uint32_t* bp = B + (size_t)b * cap;
    float a0 = 0.f, a1 = 0.f, a2 = 0.f, a3 = 0.f;
    int p = beg;
    // deep main loop: 32 edges, 8 gathers in flight per lane
    for (; p + 32 <= end; p += 32) {
        uint32_t r0 = bp[p + eq];
        uint32_t r1 = bp[p + 4 + eq];
        uint32_t r2 = bp[p + 8 + eq];
        uint32_t r3 = bp[p + 12 + eq];
        uint32_t r4 = bp[p + 16 + eq];
        uint32_t r5 = bp[p + 20 + eq];
        uint32_t r6 = bp[p + 24 + eq];
        uint32_t r7 = bp[p + 28 + eq];
        uint2 v0 = *(const uint2*)&table[r0 + fq * 2];
        uint2 v1 = *(const uint2*)&table[r1 + fq * 2];
        uint2 v2 = *(const uint2*)&table[r2 + fq * 2];
        uint2 v3 = *(const uint2*)&table[r3 + fq * 2];
        uint2 v4 = *(const uint2*)&table[r4 + fq * 2];
        uint2 v5 = *(const uint2*)&table[r5 + fq * 2];
        uint2 v6 = *(const uint2*)&table[r6 + fq * 2];
        uint2 v7 = *(const uint2*)&table[r7 + fq * 2];
        a0 += lo16f(v0.x) + lo16f(v1.x) + lo16f(v2.x) + lo16f(v3.x)
            + lo16f(v4.x) + lo16f(v5.x) + lo16f(v6.x) + lo16f(v7.x);
        a1 += hi16f(v0.x) + hi16f(v1.x) + hi16f(v2.x) + hi16f(v3.x)
            + hi16f(v4.x) + hi16f(v5.x) + hi16f(v6.x) + hi16f(v7.x);
        a2 += lo16f(v0.y) + lo16f(v1.y) + lo16f(v2.y) + lo16f(v3.y)
            + lo16f(v4.y) + lo16f(v5.y) + lo16f(v6.y) + lo16f(v7.y);
        a3 += hi16f(v0.y) + hi16f(v1.y) + hi16f(v2.y) + hi16f(v3.y)
            + hi16f(v4.y) + hi16f(v5.y) + hi16f(v6.y) + hi16f(v7.y);
    }
    for (; p + 8 <= end; p += 8) {
        uint32_t r0 = bp[p + eq];
        uint32_t r1 = bp[p + 4 + eq];
        uint2 v0 = *(const uint2*)&table[r0 + fq * 2];
        uint2 v1 = *(const uint2*)&table[r1 + fq * 2];
        a0 += lo16f(v0.x) + lo16f(v1.x);
        a1 += hi16f(v0.x) + hi16f(v1.x);
        a2 += lo16f(v0.y) + lo16f(v1.y);
        a3 += hi16f(v0.y) + hi16f(v1.y);
    }
    if (p + 4 <= end) {
        uint32_t r = bp[p + eq];
        uint2 v = *(const uint2*)&table[r + fq * 2];
        a0 += lo16f(v.x); a1 += hi16f(v.x); a2 += lo16f(v.y); a3 += hi16f(v.y);
        p += 4;
    }
    if (eq < end - p) {
        uint32_t r = bp[p + eq];
        uint2 v = *(const uint2*)&table[r + fq * 2];
        a0 += lo16f(v.x); a1 += hi16f(v.x); a2 += lo16f(v.y); a3 += hi16f(v.y);
    }
    a0 += __shfl_xor(a0, 16, 64); a0 += __shfl_xor(a0, 32, 64);
    a1 += __shfl_xor(a1, 16, 64); a1 += __shfl_xor(a1, 32, 64);
    a2 += __shfl_xor(a2, 16, 64); a2 += __shfl_xor(a2, 32, 64);
    a3 += __shfl_xor(a3, 16, 64); a3 += __shfl_xor(a3, 32, 64);
    if (lane < 16) {
        int deg = end - beg;
        float inv = 1.f / (float)(deg > 0 ? deg : 1);
        uint2 sv = *(const uint2*)&self[(size_t)node * 32 + fq * 2];
        float4 bv = *(const float4*)&bias[fq * 4];
        float v0 = a0 * inv + bv.x + lo16f(sv.x);
        float v1 = a1 * inv + bv.y + hi16f(sv.x);
        float v2 = a2 * inv + bv.z + lo16f(sv.y);
        float v3 = a3 * inv + bv.w + hi16f(sv.y);
        if (RELU) {
            v0 = fmaxf(v0, 0.f); v1 = fmaxf(v1, 0.f);
            v2 = fmaxf(v2, 0.f); v3 = fmaxf(v3, 0.f);
        }
        *(uint2*)&out[(size_t)node * 32 + fq * 2] = make_uint2(packbf2(v0, v1), packbf2(v2, v3));
    }
}

// ---------------- merged layer-1 MFMA GEMM: 128-row blocks, 2 row-tiles/wave (b reused 4x) ----------------
__global__ __launch_bounds__(256) void gemm1_mfma(
    const float* __restrict__ Xu, const ushort* __restrict__ Wtu,
    ushort* __restrict__ Ua, ushort* __restrict__ Ub, int Mu, int GU,
    const float* __restrict__ Xm, const ushort* __restrict__ Wtm,
    ushort* __restrict__ Ma, ushort* __restrict__ Mb, int Mm)
{
    constexpr int K = 128;
    int bid = blockIdx.x;
    const float* X; const ushort* Wt; ushort *Ya, *Yb; int row0; int M;
    if (bid < GU) { X = Xu; Wt = Wtu; Ya = Ua; Yb = Ub; row0 = bid * 128; M = Mu; }
    else          { X = Xm; Wt = Wtm; Ya = Ma; Yb = Mb; row0 = (bid - GU) * 128; M = Mm; }
    int tid = threadIdx.x;
    int lane = tid & 63, wr = tid >> 6;
    int r0g = row0 + wr * 32 + (lane & 15);
    int r1g = r0g + 16;
    int kgrp = (lane >> 4) * 8;
    f32x4 acc0[8] = {}, acc1[8] = {};
#pragma unroll
    for (int ks = 0; ks < 4; ++ks) {
        int kb = kgrp + ks * 32;
        float4 z = make_float4(0.f, 0.f, 0.f, 0.f);
        float4 u0 = z, u1 = z, w0 = z, w1 = z;
        if (r0g < M) {
            u0 = *(const float4*)&X[(size_t)r0g * K + kb];
            u1 = *(const float4*)&X[(size_t)r0g * K + kb + 4];
        }
        if (r1g < M) {
            w0 = *(const float4*)&X[(size_t)r1g * K + kb];
            w1 = *(const float4*)&X[(size_t)r1g * K + kb + 4];
        }
        float xs0[8] = {u0.x, u0.y, u0.z, u0.w, u1.x, u1.y, u1.z, u1.w};
        float xs1[8] = {w0.x, w0.y, w0.z, w0.w, w1.x, w1.y, w1.z, w1.w};
        bf16x8 ah0, al0, ah1, al1;
#pragma unroll
        for (int j = 0; j < 8; ++j) {
            ushort h0 = f2b(xs0[j]);
            ah0[j] = (short)h0;
            al0[j] = (short)f2b(xs0[j] - b2f(h0));
            ushort h1 = f2b(xs1[j]);
            ah1[j] = (short)h1;
            al1[j] = (short)f2b(xs1[j] - b2f(h1));
        }
#pragma unroll
        for (int cb = 0; cb < 8; ++cb) {
            bf16x8 b = *(const bf16x8*)&Wt[(size_t)(cb * 16 + (lane & 15)) * K + kb];
            acc0[cb] = __builtin_amdgcn_mfma_f32_16x16x32_bf16(ah0, b, acc0[cb], 0, 0, 0);
            acc0[cb] = __builtin_amdgcn_mfma_f32_16x16x32_bf16(al0, b, acc0[cb], 0, 0, 0);
            acc1[cb] = __builtin_amdgcn_mfma_f32_16x16x32_bf16(ah1, b, acc1[cb], 0, 0, 0);
            acc1[cb] = __builtin_amdgcn_mfma_f32_16x16x32_bf16(al1, b, acc1[cb], 0, 0, 0);
        }
    }
#pragma unroll
    for (int cb = 0; cb < 8; ++cb) {
        ushort* Y = (cb < 4) ? Ya : Yb;
        int cc = (cb * 16 + (lane & 15)) & 63;
#pragma unroll
        for (int reg = 0; reg < 4; ++reg) {
            int g0 = row0 + wr * 32 + (lane >> 4) * 4 + reg;
            if (g0 < M) Y[(size_t)g0 * 64 + cc] = f2b(acc0[cb][reg]);
            int g1 = g0 + 16;
            if (g1 < M) Y[(size_t)g1 * 64 + cc] = f2b(acc1[cb][reg]);
        }
    }
}

// ---------------- merged layer-2 MFMA GEMM: X bf16 [M,64] direct from global ----------------
__global__ __launch_bounds__(256) void gemm2_mfma(
    const ushort* __restrict__ Xu, const ushort* __restrict__ Wtu,
    ushort* __restrict__ Ua, ushort* __restrict__ Ub, int Mu, int GU,
    const ushort* __restrict__ Xm, const ushort* __restrict__ Wtm,
    ushort* __restrict__ Ma, ushort* __restrict__ Mb, int Mm)
{
    int bid = blockIdx.x;
    const ushort* X; const ushort* Wt; ushort *Ya, *Yb; int row0;
    if (bid < GU) { X = Xu; Wt = Wtu; Ya = Ua; Yb = Ub; row0 = bid * 64; }
    else          { X = Xm; Wt = Wtm; Ya = Ma; Yb = Mb; row0 = (bid - GU) * 64; }
    int tid = threadIdx.x;
    int lane = tid & 63, wr = tid >> 6;
    int rglob = row0 + wr * 16 + (lane & 15);
    int kgrp = (lane >> 4) * 8;
    f32x4 acc[8] = {};
#pragma unroll
    for (int ks = 0; ks < 2; ++ks) {
        bf16x8 a = *(const bf16x8*)&X[(size_t)rglob * 64 + kgrp + ks * 32];
#pragma unroll
        for (int cb = 0; cb < 8; ++cb) {
            bf16x8 b = *(const bf16x8*)&Wt[(size_t)(cb * 16 + (lane & 15)) * 64 + kgrp + ks * 32];
            acc[cb] = __builtin_amdgcn_mfma_f32_16x16x32_bf16(a, b, acc[cb], 0, 0, 0);
        }
    }
#pragma unroll
    for (int cb = 0; cb < 8; ++cb) {
        ushort* Y = (cb < 4) ? Ya : Yb;
        int cc = (cb * 16 + (lane & 15)) & 63;
#pragma unroll
        for (int reg = 0; reg < 4; ++reg) {
            int grow = row0 + wr * 16 + (lane >> 4) * 4 + reg;
            Y[(size_t)grow * 64 + cc] = f2b(acc[cb][reg]);
        }
    }
}

// ---------------- edge decoder: 16 lanes/edge, uint2 loads, 2 edges per slot (8 edges/wave) ----------------
__global__ __launch_bounds__(256) void edge_dec(
    const uint32_t* __restrict__ Au, const uint32_t* __restrict__ Am,
    const int* __restrict__ ls, const int* __restrict__ ld,
    const float* __restrict__ Wd2, const float* __restrict__ bd2,
    float* __restrict__ out, int L)
{
    int e0 = blockIdx.x * 32 + (threadIdx.x >> 4) * 2;
    if (e0 >= L) return;
    int e1 = e0 + 1;
    bool has1 = (e1 < L);
    int fq = threadIdx.x & 15;
    float4 w = *(const float4*)&Wd2[fq * 4];
    uint2 a0 = *(const uint2*)&Au[(size_t)ls[e0] * 32 + fq * 2];
    uint2 m0 = *(const uint2*)&Am[(size_t)ld[e0] * 32 + fq * 2];
    uint2 a1 = make_uint2(0u, 0u), m1 = make_uint2(0u, 0u);
    if (has1) {
        a1 = *(const uint2*)&Au[(size_t)ls[e1] * 32 + fq * 2];
        m1 = *(const uint2*)&Am[(size_t)ld[e1] * 32 + fq * 2];
    }
    float v0 = fmaxf(lo16f(a0.x) + lo16f(m0.x), 0.f) * w.x
             + fmaxf(hi16f(a0.x) + hi16f(m0.x), 0.f) * w.y
             + fmaxf(lo16f(a0.y) + lo16f(m0.y), 0.f) * w.z
             + fmaxf(hi16f(a0.y) + hi16f(m0.y), 0.f) * w.w;
    float v1 = fmaxf(lo16f(a1.x) + lo16f(m1.x), 0.f) * w.x
             + fmaxf(hi16f(a1.x) + hi16f(m1.x), 0.f) * w.y
             + fmaxf(lo16f(a1.y) + lo16f(m1.y), 0.f) * w.z
             + fmaxf(hi16f(a1.y) + hi16f(m1.y), 0.f) * w.w;
#pragma unroll
    for (int msk = 8; msk >= 1; msk >>= 1) {
        v0 += __shfl_xor(v0, msk, 64);
        v1 += __shfl_xor(v1, msk, 64);
    }
    if (fq == 0) {
        float b = bd2[0];
        out[e0] = v0 + b;
        if (has1) out[e1] = v1 + b;
    }
}

// ---------------- host launcher ----------------
extern "C" void kernel_launch(void* const* d_in, const int* in_sizes, int n_in,
                              void* d_out, int out_size, void* d_ws, size_t ws_size,
                              hipStream_t stream)
{
    const float* x_user  = (const float*)d_in[0];
    const float* x_movie = (const float*)d_in[1];
    const int*   esrc    = (const int*)d_in[2];
    const int*   edst    = (const int*)d_in[3];
    const int*   lsrc    = (const int*)d_in[4];
    const int*   ldst    = (const int*)d_in[5];
    const float* W1ul = (const float*)d_in[6];
    const float* b1u  = (const float*)d_in[7];
    const float* W1ur = (const float*)d_in[8];
    const float* W1ml = (const float*)d_in[9];
    const float* b1m  = (const float*)d_in[10];
    const float* W1mr = (const float*)d_in[11];
    const float* W2ul = (const float*)d_in[12];
    const float* b2u  = (const float*)d_in[13];
    const float* W2ur = (const float*)d_in[14];
    const float* W2ml = (const float*)d_in[15];
    const float* b2m  = (const float*)d_in[16];
    const float* W2mr = (const float*)d_in[17];
    const float* Wd1  = (const float*)d_in[18];
    const float* bd1  = (const float*)d_in[19];
    const float* Wd2  = (const float*)d_in[20];
    const float* bd2  = (const float*)d_in[21];
    float* out = (float*)d_out;

    const int NU = in_sizes[0] / 128;
    const int NM = in_sizes[1] / 128;
    const int E  = in_sizes[2];
    const int L  = in_sizes[4];

    char* ws = (char*)d_ws;
    const size_t SU = (size_t)NU * 64 * 2;   // bf16 tables
    const size_t SM = (size_t)NM * 64 * 2;
    ushort* U0 = (ushort*)(ws + 0);
    ushort* U1 = (ushort*)(ws + SU);
    ushort* U2 = (ushort*)(ws + 2 * SU);
    ushort* M0 = (ushort*)(ws + 3 * SU);
    ushort* M1 = (ushort*)(ws + 3 * SU + SM);
    ushort* M2 = (ushort*)(ws + 3 * SU + 2 * SM);
    size_t o = 3 * SU + 3 * SM;
    auto align256 = [](size_t x) { return (x + 255) & ~(size_t)255; };
    o = align256(o);
    int* gcm = (int*)(ws + o); o = align256(o + (size_t)(NBM + NBU) * 4);
    int* gcu = gcm + NBM;
    uint32_t* Bm = (uint32_t*)(ws + o); o = align256(o + (size_t)NBM * CAPM * 4);
    uint32_t* Bu = (uint32_t*)(ws + o); o = align256(o + (size_t)NBU * CAPU * 4);
    int* loffm = (int*)(ws + o); o = align256(o + (size_t)NBM * (BW + 1) * 4);
    int* loffu = (int*)(ws + o); o = align256(o + (size_t)NBU * (BW + 1) * 4);
    float* cu  = (float*)(ws + o); o = align256(o + 64 * 4);    // b2m@Wd1_top + bd1
    float* cm  = (float*)(ws + o); o = align256(o + 64 * 4);    // b2u@Wd1_bot
    ushort* Wt_u  = (ushort*)(ws + o); o = align256(o + 128 * 128 * 2);  // [c][k] W1ul|W1mr
    ushort* Wt_m  = (ushort*)(ws + o); o = align256(o + 128 * 128 * 2);  // [c][k] W1ml|W1ur
    ushort* Wt2_m = (ushort*)(ws + o); o = align256(o + 128 * 64 * 2);   // [c][k] Wxu|Wym
    ushort* Wt2_u = (ushort*)(ws + o); o = align256(o + 128 * 64 * 2);   // [c][k] Wyu|Wxm

    // ---- CSR-ish build: bin -> merged sort (payload pre-scaled <<5) ----
    hipMemsetAsync(gcm, 0, (size_t)(NBM + NBU) * 4, stream);
    int nbins = (E + 8191) / 8192;
    bin_kernel<<<nbins, 256, 0, stream>>>(esrc, edst, E, gcm, gcu, Bm, Bu);
    sort_bucket2<<<NBM + NBU, 256, 0, stream>>>(Bm, gcm, loffm, Bu, gcu, loffu);

    // ---- single weight-prep launch (collapse + bf16 transposes) ----
    wprep<<<4 + 128, 256, 0, stream>>>(W2ml, W2mr, W2ul, W2ur, Wd1, bd1, b2m, b2u,
                                       W1ul, W1mr, W1ml, W1ur,
                                       Wt2_m, Wt2_u, Wt_u, Wt_m, cu, cm);

    int g1u = (NU + 127) / 128, g1m = (NM + 127) / 128;   // 1563, 625
    int gu = NU / 64, gm = NM / 64;                       // 3125, 1250 exact
    int agm = (NM + 3) / 4, agu = (NU + 3) / 4;

    // ---- layer 1: merged MFMA dual GEMM, 128-row blocks (user + movie in one launch) ----
    gemm1_mfma<<<g1u + g1m, 256, 0, stream>>>(x_user, Wt_u, U0, U1, NU, g1u,
                                              x_movie, Wt_m, M0, M1, NM);

    // ---- layer-1 aggregation (movie h_m + user h_u in one launch) ----
    agg_csr<1><<<agm + agu, 256, 0, stream>>>(
        Bm, loffm, CAPM, (const uint32_t*)U0, (const uint32_t*)M1, b1u, (uint32_t*)M2, NM, agm,
        Bu, loffu, CAPU, (const uint32_t*)M0, (const uint32_t*)U1, b1m, (uint32_t*)U2, NU);

    // ---- layer 2: merged MFMA GEMM with decoder-collapsed weights ----
    gemm2_mfma<<<gu + gm, 256, 0, stream>>>(U2, Wt2_u, U0, U1, NU, gu,
                                            M2, Wt2_m, M0, M1, NM);

    // ---- layer-2 aggregation (Am + Au in one launch) ----
    agg_csr<0><<<agm + agu, 256, 0, stream>>>(
        Bm, loffm, CAPM, (const uint32_t*)U1, (const uint32_t*)M1, cm, (uint32_t*)M2, NM, agm,
        Bu, loffu, CAPU, (const uint32_t*)M0, (const uint32_t*)U0, cu, (uint32_t*)U2, NU);

    // ---- edge decoder ----
    int gl = (L + 31) / 32;
    edge_dec<<<gl, 256, 0, stream>>>((const uint32_t*)U2, (const uint32_t*)M2,
                                     lsrc, ldst, Wd2, bd2, out, L);
}

// Round 16
// 445.112 us; speedup vs baseline: 1.0442x; 1.0442x over previous
//
#include <hip/hip_runtime.h>
#include <stdint.h>

#define BW   128      // nodes per bucket
#define NBM  625      // movie buckets  (80000/128)
#define NBU  1563     // user buckets   (ceil 200000/128)
#define CAPM 4096     // per-bucket capacity, movie (avg 3200)
#define CAPU 2048     // per-bucket capacity, user  (avg 1280)

typedef __attribute__((ext_vector_type(8))) short bf16x8;
typedef __attribute__((ext_vector_type(4))) float f32x4;

__device__ __forceinline__ float b2f(ushort u) {
    return __uint_as_float((uint32_t)u << 16);
}
__device__ __forceinline__ ushort f2b(float f) {
    uint32_t x = __float_as_uint(f);
    return (ushort)((x + 0x7FFFu + ((x >> 16) & 1u)) >> 16);   // RNE
}
__device__ __forceinline__ float lo16f(uint32_t v) { return __uint_as_float(v << 16); }
__device__ __forceinline__ float hi16f(uint32_t v) { return __uint_as_float(v & 0xFFFF0000u); }
__device__ __forceinline__ uint32_t packbf2(float x, float y) {
    return (uint32_t)f2b(x) | ((uint32_t)f2b(y) << 16);
}

// ---------------- fused: edge binning | weight prep (independent roles) ----------------
__global__ __launch_bounds__(256) void binprep(
    const int* __restrict__ src, const int* __restrict__ dst, int E, int nbins,
    int* __restrict__ gcm, int* __restrict__ gcu,
    uint32_t* __restrict__ Bm, uint32_t* __restrict__ Bu,
    const float* __restrict__ W2ml, const float* __restrict__ W2mr,
    const float* __restrict__ W2ul, const float* __restrict__ W2ur,
    const float* __restrict__ Wd1, const float* __restrict__ bd1,
    const float* __restrict__ b2m, const float* __restrict__ b2u,
    const float* __restrict__ W1ul, const float* __restrict__ W1mr,
    const float* __restrict__ W1ml, const float* __restrict__ W1ur,
    ushort* __restrict__ Wt2_m, ushort* __restrict__ Wt2_u,
    ushort* __restrict__ Wt_u, ushort* __restrict__ Wt_m,
    float* __restrict__ cu, float* __restrict__ cm)
{
    __shared__ float smem[8192];   // 32 KB union
    int bid = blockIdx.x, tid = threadIdx.x;
    if (bid < nbins) {
        // ---- bin role ----
        int* hm = (int*)smem;          // [NBM]
        int* hu = ((int*)smem) + NBM;  // [NBU]
        const int CH = 8192;
        int e0 = bid * CH;
        int e1 = min(e0 + CH, E);
        for (int b = tid; b < NBM; b += 256) hm[b] = 0;
        for (int b = tid; b < NBU; b += 256) hu[b] = 0;
        __syncthreads();
        for (int i = e0 + tid; i < e1; i += 256) {
            atomicAdd(&hm[dst[i] >> 7], 1);
            atomicAdd(&hu[src[i] >> 7], 1);
        }
        __syncthreads();
        for (int b = tid; b < NBM; b += 256) { int c = hm[b]; hm[b] = c ? atomicAdd(&gcm[b], c) : 0; }
        for (int b = tid; b < NBU; b += 256) { int c = hu[b]; hu[b] = c ? atomicAdd(&gcu[b], c) : 0; }
        __syncthreads();
        for (int i = e0 + tid; i < e1; i += 256) {
            int d = dst[i], s = src[i];
            int bm = d >> 7, bu = s >> 7;
            int pm = atomicAdd(&hm[bm], 1);
            if (pm < CAPM) Bm[(size_t)bm * CAPM + pm] = ((uint32_t)(d & 127) << 24) | (uint32_t)s;
            int pu = atomicAdd(&hu[bu], 1);
            if (pu < CAPU) Bu[(size_t)bu * CAPU + pu] = ((uint32_t)(s & 127) << 24) | (uint32_t)d;
        }
        return;
    }
    int wb = bid - nbins;
    if (wb < 4) {
        // ---- weight collapse role ----
        float* As = smem;
        float* Bs = smem + 4096;
        const float* A; int brow0; const float* bvec; const float* addb;
        ushort* WtOut; int cofs; float* outc;
        if (wb == 0)      { A = W2ml; brow0 = 0;  bvec = b2m; addb = bd1;    WtOut = Wt2_m; cofs = 0;  outc = cu; }
        else if (wb == 1) { A = W2mr; brow0 = 0;  bvec = 0;   addb = 0;      WtOut = Wt2_u; cofs = 0;  outc = 0;  }
        else if (wb == 2) { A = W2ul; brow0 = 64; bvec = b2u; addb = 0;      WtOut = Wt2_u; cofs = 64; outc = cm; }
        else              { A = W2ur; brow0 = 64; bvec = 0;   addb = 0;      WtOut = Wt2_m; cofs = 64; outc = 0;  }
        for (int i = tid; i < 4096; i += 256) {
            As[i] = A[i];
            Bs[i] = Wd1[(size_t)(brow0 + (i >> 6)) * 64 + (i & 63)];
        }
        __syncthreads();
        int r = tid >> 2, c0 = (tid & 3) * 16;
        float acc[16] = {};
        for (int k = 0; k < 64; ++k) {
            float a = As[r * 64 + k];
            const float* bp = &Bs[k * 64 + c0];
#pragma unroll
            for (int j = 0; j < 16; ++j) acc[j] += a * bp[j];
        }
#pragma unroll
        for (int j = 0; j < 16; ++j)
            WtOut[(size_t)(cofs + c0 + j) * 64 + r] = f2b(acc[j]);   // [c][k] bf16, transposed
        if (outc && tid < 64) {
            float s = addb ? addb[tid] : 0.f;
            for (int k = 0; k < 64; ++k) s += bvec[k] * Bs[k * 64 + tid];
            outc[tid] = s;
        }
    } else {
        // ---- layer-1 weight transpose role ----
        int t = wb - 4;
        const float *Wa, *Wb; ushort* Wt;
        if (t < 64) { Wa = W1ul; Wb = W1mr; Wt = Wt_u; }
        else        { Wa = W1ml; Wb = W1ur; Wt = Wt_m; t -= 64; }
        int idx = t * 256 + tid;           // 0 .. 16383 = 128 cols x 128 k
        int c = idx >> 7, k = idx & 127;
        Wt[idx] = f2b((c < 64 ? Wa : Wb)[(size_t)k * 64 + (c & 63)]);
    }
}

// ---------------- fused: layer-1 MFMA GEMM (first) | per-bucket counting sort ----------------
__global__ __launch_bounds__(256) void sortgemm1(
    const float* __restrict__ Xu, const ushort* __restrict__ Wtu,
    ushort* __restrict__ Ua, ushort* __restrict__ Ub, int Mu, int GU,
    const float* __restrict__ Xm, const ushort* __restrict__ Wtm,
    ushort* __restrict__ Ma, ushort* __restrict__ Mb, int Mm, int NG,
    uint32_t* __restrict__ Bm, const int* __restrict__ gcm, int* __restrict__ loffm,
    uint32_t* __restrict__ Bu, const int* __restrict__ gcu, int* __restrict__ loffu)
{
    __shared__ uint32_t smem[2 * CAPM + 3 * BW + 1];   // ~33.5 KB union
    int bid = blockIdx.x, tid = threadIdx.x;
    if (bid < NG) {
        // ---- gemm1 role: 128-row blocks, 2 row-tiles/wave, reg-direct hi/lo bf16 split ----
        constexpr int K = 128;
        const float* X; const ushort* Wt; ushort *Ya, *Yb; int row0; int M;
        if (bid < GU) { X = Xu; Wt = Wtu; Ya = Ua; Yb = Ub; row0 = bid * 128; M = Mu; }
        else          { X = Xm; Wt = Wtm; Ya = Ma; Yb = Mb; row0 = (bid - GU) * 128; M = Mm; }
        int lane = tid & 63, wr = tid >> 6;
        int r0g = row0 + wr * 32 + (lane & 15);
        int r1g = r0g + 16;
        int kgrp = (lane >> 4) * 8;
        f32x4 acc0[8] = {}, acc1[8] = {};
#pragma unroll
        for (int ks = 0; ks < 4; ++ks) {
            int kb = kgrp + ks * 32;
            float4 z = make_float4(0.f, 0.f, 0.f, 0.f);
            float4 u0 = z, u1 = z, w0 = z, w1 = z;
            if (r0g < M) {
                u0 = *(const float4*)&X[(size_t)r0g * K + kb];
                u1 = *(const float4*)&X[(size_t)r0g * K + kb + 4];
            }
            if (r1g < M) {
                w0 = *(const float4*)&X[(size_t)r1g * K + kb];
                w1 = *(const float4*)&X[(size_t)r1g * K + kb + 4];
            }
            float xs0[8] = {u0.x, u0.y, u0.z, u0.w, u1.x, u1.y, u1.z, u1.w};
            float xs1[8] = {w0.x, w0.y, w0.z, w0.w, w1.x, w1.y, w1.z, w1.w};
            bf16x8 ah0, al0, ah1, al1;
#pragma unroll
            for (int j = 0; j < 8; ++j) {
                ushort h0 = f2b(xs0[j]);
                ah0[j] = (short)h0;
                al0[j] = (short)f2b(xs0[j] - b2f(h0));
                ushort h1 = f2b(xs1[j]);
                ah1[j] = (short)h1;
                al1[j] = (short)f2b(xs1[j] - b2f(h1));
            }
#pragma unroll
            for (int cb = 0; cb < 8; ++cb) {
                bf16x8 b = *(const bf16x8*)&Wt[(size_t)(cb * 16 + (lane & 15)) * K + kb];
                acc0[cb] = __builtin_amdgcn_mfma_f32_16x16x32_bf16(ah0, b, acc0[cb], 0, 0, 0);
                acc0[cb] = __builtin_amdgcn_mfma_f32_16x16x32_bf16(al0, b, acc0[cb], 0, 0, 0);
                acc1[cb] = __builtin_amdgcn_mfma_f32_16x16x32_bf16(ah1, b, acc1[cb], 0, 0, 0);
                acc1[cb] = __builtin_amdgcn_mfma_f32_16x16x32_bf16(al1, b, acc1[cb], 0, 0, 0);
            }
        }
#pragma unroll
        for (int cb = 0; cb < 8; ++cb) {
            ushort* Y = (cb < 4) ? Ya : Yb;
            int cc = (cb * 16 + (lane & 15)) & 63;
#pragma unroll
            for (int reg = 0; reg < 4; ++reg) {
                int g0 = row0 + wr * 32 + (lane >> 4) * 4 + reg;
                if (g0 < M) Y[(size_t)g0 * 64 + cc] = f2b(acc0[cb][reg]);
                int g1 = g0 + 16;
                if (g1 < M) Y[(size_t)g1 * 64 + cc] = f2b(acc1[cb][reg]);
            }
        }
        return;
    }
    // ---- sort role: per-bucket counting sort -> node-ordered payload(<<5) + local offsets ----
    int sbid = bid - NG;
    uint32_t* rec = smem;
    uint32_t* srt = smem + CAPM;
    int* hist = (int*)(smem + 2 * CAPM);
    int* hoff = hist + BW;          // [BW+1]
    int* cur  = hoff + BW + 1;      // [BW]
    uint32_t* B; const int* gc; int* loff; int cap; int b;
    if (sbid < NBM) { B = Bm; gc = gcm; loff = loffm; cap = CAPM; b = sbid; }
    else            { B = Bu; gc = gcu; loff = loffu; cap = CAPU; b = sbid - NBM; }
    int cnt = min(gc[b], cap);
    uint32_t* bp = B + (size_t)b * cap;
    for (int i = tid; i < cnt; i += 256) rec[i] = bp[i];
    if (tid < BW) hist[tid] = 0;
    __syncthreads();
    for (int i = tid; i < cnt; i += 256) atomicAdd(&hist[rec[i] >> 24], 1);
    __syncthreads();
    if (tid == 0) {
        int s = 0;
        for (int i = 0; i < BW; ++i) { hoff[i] = s; s += hist[i]; }
        hoff[BW] = s;
    }
    __syncthreads();
    if (tid < BW) cur[tid] = hoff[tid];
    __syncthreads();
    for (int i = tid; i < cnt; i += 256) {
        uint32_t r = rec[i];
        int pos = atomicAdd(&cur[r >> 24], 1);
        srt[pos] = (r & 0xFFFFFFu) << 5;   // pre-scaled: uint32-word offset of table row
    }
    __syncthreads();
    for (int i = tid; i < cnt; i += 256) bp[i] = srt[i];
    for (int i = tid; i <= BW; i += 256) loff[(size_t)b * (BW + 1) + i] = hoff[i];
}

// ---------------- merged wave-per-node mean-aggregate: 16 lanes/edge, uint2, 16-deep (round-14 proven) ----------------
template<int RELU>
__global__ __launch_bounds__(256) void agg_csr(
    const uint32_t* __restrict__ Ba, const int* __restrict__ loffa, int capa,
    const uint32_t* __restrict__ ta, const uint32_t* __restrict__ sa,
    const float* __restrict__ biasa, uint32_t* __restrict__ oa, int na, int GA,
    const uint32_t* __restrict__ Bb, const int* __restrict__ loffb, int capb,
    const uint32_t* __restrict__ tb, const uint32_t* __restrict__ sb,
    const float* __restrict__ biasb, uint32_t* __restrict__ ob, int nb)
{
    int bid = blockIdx.x;
    const uint32_t* B; const int* loff; int cap;
    const uint32_t* table; const uint32_t* self; const float* bias;
    uint32_t* out; int n_nodes; int lb;
    if (bid < GA) { B = Ba; loff = loffa; cap = capa; table = ta; self = sa; bias = biasa; out = oa; n_nodes = na; lb = bid; }
    else          { B = Bb; loff = loffb; cap = capb; table = tb; self = sb; bias = biasb; out = ob; n_nodes = nb; lb = bid - GA; }
    int node = lb * 4 + (threadIdx.x >> 6);
    if (node >= n_nodes) return;
    int lane = threadIdx.x & 63;
    int eq = lane >> 4;           // edge slot 0..3
    int fq = lane & 15;           // feature quad (4 bf16 = uint2)
    int b = node >> 7, l = node & 127;
    const int* lo = loff + (size_t)b * (BW + 1);
    int beg = lo[l], end = lo[l + 1];
    const uint32_t* bp = B + (size_t)b * cap;
    float a0 = 0.f, a1 = 0.f, a2 = 0.f, a3 = 0.f;
    int p = beg;
    // deep main loop: 16 edges, 4 gathers in flight per lane
    for (; p + 16 <= end; p += 16) {
        uint32_t r0 = bp[p + eq];
        uint32_t r1 = bp[p + 4 + eq];
        uint32_t r2 = bp[p + 8 + eq];
        uint32_t r3 = bp[p + 12 + eq];
        uint2 v0 = *(const uint2*)&table[r0 + fq * 2];
        uint2 v1 = *(const uint2*)&table[r1 + fq * 2];
        uint2 v2 = *(const uint2*)&table[r2 + fq * 2];
        uint2 v3 = *(const uint2*)&table[r3 + fq * 2];
        a0 += lo16f(v0.x) + lo16f(v1.x) + lo16f(v2.x) + lo16f(v3.x);
        a1 += hi16f(v0.x) + hi16f(v1.x) + hi16f(v2.x) + hi16f(v3.x);
        a2 += lo16f(v0.y) + lo16f(v1.y) + lo16f(v2.y) + lo16f(v3.y);
        a3 += hi16f(v0.y) + hi16f(v1.y) + hi16f(v2.y) + hi16f(v3.y);
    }
    for (; p + 8 <= end; p += 8) {
        uint32_t r0 = bp[p + eq];
        uint32_t r1 = bp[p + 4 + eq];
        uint2 v0 = *(const uint2*)&table[r0 + fq * 2];
        uint2 v1 = *(const uint2*)&table[r1 + fq * 2];
        a0 += lo16f(v0.x) + lo16f(v1.x);
        a1 += hi16f(v0.x) + hi16f(v1.x);
        a2 += lo16f(v0.y) + lo16f(v1.y);
        a3 += hi16f(v0.y) + hi16f(v1.y);
    }
    if (p + 4 <= end) {
        uint32_t r = bp[p + eq];
        uint2 v = *(const uint2*)&table[r + fq * 2];
        a0 += lo16f(v.x); a1 += hi16f(v.x); a2 += lo16f(v.y); a3 += hi16f(v.y);
        p += 4;
    }
    if (eq < end - p) {
        uint32_t r = bp[p + eq];
        uint2 v = *(const uint2*)&table[r + fq * 2];
        a0 += lo16f(v.x); a1 += hi16f(v.x); a2 += lo16f(v.y); a3 += hi16f(v.y);
    }
    a0 += __shfl_xor(a0, 16, 64); a0 += __shfl_xor(a0, 32, 64);
    a1 += __shfl_xor(a1, 16, 64); a1 += __shfl_xor(a1, 32, 64);
    a2 += __shfl_xor(a2, 16, 64); a2 += __shfl_xor(a2, 32, 64);
    a3 += __shfl_xor(a3, 16, 64); a3 += __shfl_xor(a3, 32, 64);
    if (lane < 16) {
        int deg = end - beg;
        float inv = 1.f / (float)(deg > 0 ? deg : 1);
        uint2 sv = *(const uint2*)&self[(size_t)node * 32 + fq * 2];
        float4 bv = *(const float4*)&bias[fq * 4];
        float v0 = a0 * inv + bv.x + lo16f(sv.x);
        float v1 = a1 * inv + bv.y + hi16f(sv.x);
        float v2 = a2 * inv + bv.z + lo16f(sv.y);
        float v3 = a3 * inv + bv.w + hi16f(sv.y);
        if (RELU) {
            v0 = fmaxf(v0, 0.f); v1 = fmaxf(v1, 0.f);
            v2 = fmaxf(v2, 0.f); v3 = fmaxf(v3, 0.f);
        }
        *(uint2*)&out[(size_t)node * 32 + fq * 2] = make_uint2(packbf2(v0, v1), packbf2(v2, v3));
    }
}

// ---------------- merged layer-2 MFMA GEMM: X bf16 [M,64] direct from global ----------------
__global__ __launch_bounds__(256) void gemm2_mfma(
    const ushort* __restrict__ Xu, const ushort* __restrict__ Wtu,
    ushort* __restrict__ Ua, ushort* __restrict__ Ub, int Mu, int GU,
    const ushort* __restrict__ Xm, const ushort* __restrict__ Wtm,
    ushort* __restrict__ Ma, ushort* __restrict__ Mb, int Mm)
{
    int bid = blockIdx.x;
    const ushort* X; const ushort* Wt; ushort *Ya, *Yb; int row0;
    if (bid < GU) { X = Xu; Wt = Wtu; Ya = Ua; Yb = Ub; row0 = bid * 64; }
    else          { X = Xm; Wt = Wtm; Ya = Ma; Yb = Mb; row0 = (bid - GU) * 64; }
    int tid = threadIdx.x;
    int lane = tid & 63, wr = tid >> 6;
    int rglob = row0 + wr * 16 + (lane & 15);
    int kgrp = (lane >> 4) * 8;
    f32x4 acc[8] = {};
#pragma unroll
    for (int ks = 0; ks < 2; ++ks) {
        bf16x8 a = *(const bf16x8*)&X[(size_t)rglob * 64 + kgrp + ks * 32];
#pragma unroll
        for (int cb = 0; cb < 8; ++cb) {
            bf16x8 b = *(const bf16x8*)&Wt[(size_t)(cb * 16 + (lane & 15)) * 64 + kgrp + ks * 32];
            acc[cb] = __builtin_amdgcn_mfma_f32_16x16x32_bf16(a, b, acc[cb], 0, 0, 0);
        }
    }
#pragma unroll
    for (int cb = 0; cb < 8; ++cb) {
        ushort* Y = (cb < 4) ? Ya : Yb;
        int cc = (cb * 16 + (lane & 15)) & 63;
#pragma unroll
        for (int reg = 0; reg < 4; ++reg) {
            int grow = row0 + wr * 16 + (lane >> 4) * 4 + reg;
            Y[(size_t)grow * 64 + cc] = f2b(acc[cb][reg]);
        }
    }
}

// ---------------- edge decoder: 16 lanes/edge, uint2 loads, 2 edges per slot (8 edges/wave) ----------------
__global__ __launch_bounds__(256) void edge_dec(
    const uint32_t* __restrict__ Au, const uint32_t* __restrict__ Am,
    const int* __restrict__ ls, const int* __restrict__ ld,
    const float* __restrict__ Wd2, const float* __restrict__ bd2,
    float* __restrict__ out, int L)
{
    int e0 = blockIdx.x * 32 + (threadIdx.x >> 4) * 2;
    if (e0 >= L) return;
    int e1 = e0 + 1;
    bool has1 = (e1 < L);
    int fq = threadIdx.x & 15;
    float4 w = *(const float4*)&Wd2[fq * 4];
    uint2 a0 = *(const uint2*)&Au[(size_t)ls[e0] * 32 + fq * 2];
    uint2 m0 = *(const uint2*)&Am[(size_t)ld[e0] * 32 + fq * 2];
    uint2 a1 = make_uint2(0u, 0u), m1 = make_uint2(0u, 0u);
    if (has1) {
        a1 = *(const uint2*)&Au[(size_t)ls[e1] * 32 + fq * 2];
        m1 = *(const uint2*)&Am[(size_t)ld[e1] * 32 + fq * 2];
    }
    float v0 = fmaxf(lo16f(a0.x) + lo16f(m0.x), 0.f) * w.x
             + fmaxf(hi16f(a0.x) + hi16f(m0.x), 0.f) * w.y
             + fmaxf(lo16f(a0.y) + lo16f(m0.y), 0.f) * w.z
             + fmaxf(hi16f(a0.y) + hi16f(m0.y), 0.f) * w.w;
    float v1 = fmaxf(lo16f(a1.x) + lo16f(m1.x), 0.f) * w.x
             + fmaxf(hi16f(a1.x) + hi16f(m1.x), 0.f) * w.y
             + fmaxf(lo16f(a1.y) + lo16f(m1.y), 0.f) * w.z
             + fmaxf(hi16f(a1.y) + hi16f(m1.y), 0.f) * w.w;
#pragma unroll
    for (int msk = 8; msk >= 1; msk >>= 1) {
        v0 += __shfl_xor(v0, msk, 64);
        v1 += __shfl_xor(v1, msk, 64);
    }
    if (fq == 0) {
        float b = bd2[0];
        out[e0] = v0 + b;
        if (has1) out[e1] = v1 + b;
    }
}

// ---------------- host launcher ----------------
extern "C" void kernel_launch(void* const* d_in, const int* in_sizes, int n_in,
                              void* d_out, int out_size, void* d_ws, size_t ws_size,
                              hipStream_t stream)
{
    const float* x_user  = (const float*)d_in[0];
    const float* x_movie = (const float*)d_in[1];
    const int*   esrc    = (const int*)d_in[2];
    const int*   edst    = (const int*)d_in[3];
    const int*   lsrc    = (const int*)d_in[4];
    const int*   ldst    = (const int*)d_in[5];
    const float* W1ul = (const float*)d_in[6];
    const float* b1u  = (const float*)d_in[7];
    const float* W1ur = (const float*)d_in[8];
    const float* W1ml = (const float*)d_in[9];
    const float* b1m  = (const float*)d_in[10];
    const float* W1mr = (const float*)d_in[11];
    const float* W2ul = (const float*)d_in[12];
    const float* b2u  = (const float*)d_in[13];
    const float* W2ur = (const float*)d_in[14];
    const float* W2ml = (const float*)d_in[15];
    const float* b2m  = (const float*)d_in[16];
    const float* W2mr = (const float*)d_in[17];
    const float* Wd1  = (const float*)d_in[18];
    const float* bd1  = (const float*)d_in[19];
    const float* Wd2  = (const float*)d_in[20];
    const float* bd2  = (const float*)d_in[21];
    float* out = (float*)d_out;

    const int NU = in_sizes[0] / 128;
    const int NM = in_sizes[1] / 128;
    const int E  = in_sizes[2];
    const int L  = in_sizes[4];

    char* ws = (char*)d_ws;
    const size_t SU = (size_t)NU * 64 * 2;   // bf16 tables
    const size_t SM = (size_t)NM * 64 * 2;
    ushort* U0 = (ushort*)(ws + 0);
    ushort* U1 = (ushort*)(ws + SU);
    ushort* U2 = (ushort*)(ws + 2 * SU);
    ushort* M0 = (ushort*)(ws + 3 * SU);
    ushort* M1 = (ushort*)(ws + 3 * SU + SM);
    ushort* M2 = (ushort*)(ws + 3 * SU + 2 * SM);
    size_t o = 3 * SU + 3 * SM;
    auto align256 = [](size_t x) { return (x + 255) & ~(size_t)255; };
    o = align256(o);
    int* gcm = (int*)(ws + o); o = align256(o + (size_t)(NBM + NBU) * 4);
    int* gcu = gcm + NBM;
    uint32_t* Bm = (uint32_t*)(ws + o); o = align256(o + (size_t)NBM * CAPM * 4);
    uint32_t* Bu = (uint32_t*)(ws + o); o = align256(o + (size_t)NBU * CAPU * 4);
    int* loffm = (int*)(ws + o); o = align256(o + (size_t)NBM * (BW + 1) * 4);
    int* loffu = (int*)(ws + o); o = align256(o + (size_t)NBU * (BW + 1) * 4);
    float* cu  = (float*)(ws + o); o = align256(o + 64 * 4);    // b2m@Wd1_top + bd1
    float* cm  = (float*)(ws + o); o = align256(o + 64 * 4);    // b2u@Wd1_bot
    ushort* Wt_u  = (ushort*)(ws + o); o = align256(o + 128 * 128 * 2);  // [c][k] W1ul|W1mr
    ushort* Wt_m  = (ushort*)(ws + o); o = align256(o + 128 * 128 * 2);  // [c][k] W1ml|W1ur
    ushort* Wt2_m = (ushort*)(ws + o); o = align256(o + 128 * 64 * 2);   // [c][k] Wxu|Wym
    ushort* Wt2_u = (ushort*)(ws + o); o = align256(o + 128 * 64 * 2);   // [c][k] Wyu|Wxm

    int g1u = (NU + 127) / 128, g1m = (NM + 127) / 128;   // 1563, 625
    int gu = NU / 64, gm = NM / 64;                       // 3125, 1250 exact
    int agm = (NM + 3) / 4, agu = (NU + 3) / 4;
    int nbins = (E + 8191) / 8192;

    // ---- fused: bin | weight-prep (independent) ----
    hipMemsetAsync(gcm, 0, (size_t)(NBM + NBU) * 4, stream);
    binprep<<<nbins + 132, 256, 0, stream>>>(esrc, edst, E, nbins, gcm, gcu, Bm, Bu,
                                             W2ml, W2mr, W2ul, W2ur, Wd1, bd1, b2m, b2u,
                                             W1ul, W1mr, W1ml, W1ur,
                                             Wt2_m, Wt2_u, Wt_u, Wt_m, cu, cm);

    // ---- fused: layer-1 MFMA dual GEMM (first) | bucket sort ----
    sortgemm1<<<(g1u + g1m) + (NBM + NBU), 256, 0, stream>>>(
        x_user, Wt_u, U0, U1, NU, g1u,
        x_movie, Wt_m, M0, M1, NM, g1u + g1m,
        Bm, gcm, loffm, Bu, gcu, loffu);

    // ---- layer-1 aggregation (movie h_m + user h_u in one launch) ----
    agg_csr<1><<<agm + agu, 256, 0, stream>>>(
        Bm, loffm, CAPM, (const uint32_t*)U0, (const uint32_t*)M1, b1u, (uint32_t*)M2, NM, agm,
        Bu, loffu, CAPU, (const uint32_t*)M0, (const uint32_t*)U1, b1m, (uint32_t*)U2, NU);

    // ---- layer 2: merged MFMA GEMM with decoder-collapsed weights ----
    gemm2_mfma<<<gu + gm, 256, 0, stream>>>(U2, Wt2_u, U0, U1, NU, gu,
                                            M2, Wt2_m, M0, M1, NM);

    // ---- layer-2 aggregation (Am + Au in one launch) ----
    agg_csr<0><<<agm + agu, 256, 0, stream>>>(
        Bm, loffm, CAPM, (const uint32_t*)U1, (const uint32_t*)M1, cm, (uint32_t*)M2, NM, agm,
        Bu, loffu, CAPU, (const uint32_t*)M0, (const uint32_t*)U0, cu, (uint32_t*)U2, NU);

    // ---- edge decoder ----
    int gl = (L + 31) / 32;
    edge_dec<<<gl, 256, 0, stream>>>((const uint32_t*)U2, (const uint32_t*)M2,
                                     lsrc, ldst, Wd2, bd2, out, L);
}